// Round 16
// baseline (35409.402 us; speedup 1.0000x reference)
//
#include <hip/hip_runtime.h>

#define SEQ    2048
#define BATCH  64
#define DIN    512
#define HID    512
#define GATES  2048
#define NB     64      // block k owns 8 hidden cols -> 32 gate cols
#define NT     256     // 4 waves; wave w owns batch rows [16w,16w+16)

typedef short bf16v8 __attribute__((ext_vector_type(8)));
typedef float f32x4  __attribute__((ext_vector_type(4)));

static __device__ __forceinline__ unsigned short f2bfbits(float f) {
    union { __bf16 h; unsigned short s; } u;
    u.h = (__bf16)f;           // RNE
    return u.s;
}

static __device__ __forceinline__ bf16v8 cvt8(const float* __restrict__ p) {
    float4 a = *(const float4*)(p);
    float4 b = *(const float4*)(p + 4);
    union { __bf16 h[8]; bf16v8 v; } u;
    u.h[0] = (__bf16)a.x; u.h[1] = (__bf16)a.y;
    u.h[2] = (__bf16)a.z; u.h[3] = (__bf16)a.w;
    u.h[4] = (__bf16)b.x; u.h[5] = (__bf16)b.y;
    u.h[6] = (__bf16)b.z; u.h[7] = (__bf16)b.w;
    return u.v;
}

static __device__ __forceinline__ float sigm(float v) {
    return 1.0f / (1.0f + __expf(-v));
}
static __device__ __forceinline__ float ftanh(float v) {
    return 1.0f - 2.0f / (__expf(2.0f * v) + 1.0f);   // exact limits via __expf
}

// ============== v15: one kernel per timestep, graph-sequenced ===============
// After 13 persistent-kernel rounds, every hand-rolled grid rendezvous sits
// at a ~10us/step floor (best v12 = 10.8us; compute ~1.5us). Pivot: use
// KERNEL BOUNDARIES as the barrier -- the AQL packet processor provides
// release/acquire + cross-XCD coherence in hardware, pipelined with dispatch.
// 2049 graph nodes; h/c flow through d_ws with zero explicit sync. Math body
// = round-1's proven kernel (fused x@Wi + h@Wh per step).

__global__ void __launch_bounds__(NT, 1) lstm_init(
    const float* __restrict__ c0, const float* __restrict__ h0,
    unsigned short* __restrict__ hb, float* __restrict__ cb)
{
    for (int i = blockIdx.x * NT + threadIdx.x; i < BATCH * HID; i += NB * NT) {
        hb[i] = f2bfbits(h0[i]);   // h_0 -> bf16 buffer 0
        cb[i] = c0[i];
    }
}

__global__ void __launch_bounds__(NT, 1) lstm_step(
    const float* __restrict__ x,  const float* __restrict__ Wi,
    const float* __restrict__ Wh, const float* __restrict__ bias,
    float* __restrict__ out, unsigned short* __restrict__ hws,
    float* __restrict__ cb, int t)
{
    // 32 cols x 512 K each, bf16, col-major, XOR-swizzled 16B k-groups. 64 KiB.
    __shared__ unsigned short wi_lds[32 * 512];
    __shared__ unsigned short wh_lds[32 * 512];

    const int tid   = threadIdx.x;
    const int blk   = blockIdx.x;
    const int lane  = tid & 63;
    const int wv    = tid >> 6;
    const int col   = lane & 15;       // MFMA n / C-col index
    const int rgrp  = lane >> 4;       // k-group / C-row group
    const int c7    = col & 7;
    const int hbase = blk * 8;

    // ---- per-kernel: weight slices -> LDS (bf16, swizzled). L2-hot. ----
    for (int idx = tid; idx < 32 * 512; idx += NT) {
        const int c = idx & 31;                          // local gate col
        const int k = idx >> 5;                          // 0..511
        const int gc = (c >> 3) * HID + hbase + (c & 7); // global col in 4H
        const int sidx = c * 512 + ((((k >> 3) ^ (c & 7)) << 3) | (k & 7));
        wi_lds[sidx] = f2bfbits(Wi[(size_t)k * GATES + gc]);
        wh_lds[sidx] = f2bfbits(Wh[(size_t)k * GATES + gc]);
    }
    __syncthreads();

    const unsigned short* hr = hws + (t & 1) * (BATCH * HID);
    unsigned short*       hw = hws + ((t + 1) & 1) * (BATCH * HID);

    const int brow_a = wv * 16 + col;   // A-fragment batch row for this lane
    const int hcol   = hbase + col;     // (active lanes: col<8)
    const float bv0 = bias[(col >> 3) * HID + hbase + c7];
    const float bv1 = bias[((col + 16) >> 3) * HID + hbase + c7];

    const float*          xrow = x + ((size_t)t * BATCH + brow_a) * DIN;
    const unsigned short* hrow = hr + brow_a * HID;

    f32x4 acc0 = {0.f, 0.f, 0.f, 0.f};   // cols 0..15  (i, f)
    f32x4 acc1 = {0.f, 0.f, 0.f, 0.f};   // cols 16..31 (g, o)

    #pragma unroll
    for (int ks = 0; ks < 16; ++ks) {
        const int kofs = ks * 32 + rgrp * 8;
        const bf16v8 ah = *(const bf16v8*)(hrow + kofs);
        const bf16v8 ax = cvt8(xrow + kofs);
        const int gsw = (((ks * 4 + rgrp) ^ c7) << 3);
        const bf16v8 bwi0 = *(const bf16v8*)(wi_lds + col * 512 + gsw);
        const bf16v8 bwh0 = *(const bf16v8*)(wh_lds + col * 512 + gsw);
        const bf16v8 bwi1 = *(const bf16v8*)(wi_lds + (col + 16) * 512 + gsw);
        const bf16v8 bwh1 = *(const bf16v8*)(wh_lds + (col + 16) * 512 + gsw);
        acc0 = __builtin_amdgcn_mfma_f32_16x16x32_bf16(ax, bwi0, acc0, 0, 0, 0);
        acc0 = __builtin_amdgcn_mfma_f32_16x16x32_bf16(ah, bwh0, acc0, 0, 0, 0);
        acc1 = __builtin_amdgcn_mfma_f32_16x16x32_bf16(ax, bwi1, acc1, 0, 0, 0);
        acc1 = __builtin_amdgcn_mfma_f32_16x16x32_bf16(ah, bwh1, acc1, 0, 0, 0);
    }

    // ---- gates; C/D layout: col = lane&15, row = (lane>>4)*4 + r ----
    float z0[4], z1[4], zf[4], zo[4];
    #pragma unroll
    for (int r = 0; r < 4; ++r) { z0[r] = acc0[r] + bv0; z1[r] = acc1[r] + bv1; }
    #pragma unroll
    for (int r = 0; r < 4; ++r) {
        zf[r] = __shfl_xor(z0[r], 8);   // partner col+8: f gate
        zo[r] = __shfl_xor(z1[r], 8);   // partner col+24: o gate
    }

    if (col < 8) {
        const size_t YS = 2 * (size_t)BATCH * HID;
        #pragma unroll
        for (int r = 0; r < 4; ++r) {
            const int brow = wv * 16 + rgrp * 4 + r;
            const float ig = sigm(z0[r]);
            const float fg = sigm(zf[r]);
            const float gg = ftanh(z1[r]);
            const float og = sigm(zo[r]);
            const float cn = fg * cb[brow * HID + hcol] + ig * gg;
            cb[brow * HID + hcol] = cn;
            const float hn = og * ftanh(cn);
            hw[brow * HID + hcol] = f2bfbits(hn);
            out[YS + ((size_t)t * BATCH + brow) * HID + hcol] = hn;
            if (t == SEQ - 1) {
                out[(size_t)brow * HID + hcol] = cn;                      // cT
                out[(size_t)BATCH * HID + brow * HID + hcol] = hn;        // hT
            }
        }
    }
}

extern "C" void kernel_launch(void* const* d_in, const int* in_sizes, int n_in,
                              void* d_out, int out_size, void* d_ws, size_t ws_size,
                              hipStream_t stream) {
    const float* x  = (const float*)d_in[0];
    const float* c0 = (const float*)d_in[1];
    const float* h0 = (const float*)d_in[2];
    const float* Wi = (const float*)d_in[3];
    const float* Wh = (const float*)d_in[4];
    const float* b  = (const float*)d_in[5];
    float* out = (float*)d_out;

    // ws: [0,128K) h double buffer [2][64][512] bf16 | [128K,256K) c [64][512] f32
    char* wsb = (char*)d_ws;
    unsigned short* hws = (unsigned short*)wsb;
    float*          cb  = (float*)(wsb + 2 * BATCH * HID * sizeof(unsigned short));

    lstm_init<<<dim3(NB), dim3(NT), 0, stream>>>(c0, h0, hws, cb);
    for (int t = 0; t < SEQ; ++t)
        lstm_step<<<dim3(NB), dim3(NT), 0, stream>>>(x, Wi, Wh, b, out, hws, cb, t);
}